// Round 1
// baseline (1085.397 us; speedup 1.0000x reference)
//
#include <hip/hip_runtime.h>

#define Bn 512
#define Tn 256
#define Cn 384
#define Hn 384
#define Mn (Bn*Tn)      // 131072 rows
#define N3 1152         // [k|v|q] columns

typedef _Float16 f16x8 __attribute__((ext_vector_type(8)));
typedef float    f32x4 __attribute__((ext_vector_type(4)));
typedef unsigned short u16;
typedef unsigned int   u32;

__device__ inline u16 f2h(float f){
  _Float16 h = (_Float16)f;          // RNE
  return __builtin_bit_cast(u16, h);
}

__device__ inline void gl_lds16(const void* g, void* l){
  __builtin_amdgcn_global_load_lds(
      (const __attribute__((address_space(1))) u32*)g,
      (__attribute__((address_space(3))) u32*)l, 16, 0, 0);
}

// ---------- kernel 0: x fp32 -> fp16 ----------
__global__ __launch_bounds__(256) void k_convert_x(const float* __restrict__ x,
                                                   u16* __restrict__ xh){
  const size_t i8 = (size_t)blockIdx.x*256 + threadIdx.x;  // 8 elems each
  const float4* xp = (const float4*)x;
  float4 a = xp[i8*2], b = xp[i8*2+1];
  union { uint4 u; u16 s[8]; } o;
  o.s[0]=f2h(a.x); o.s[1]=f2h(a.y); o.s[2]=f2h(a.z); o.s[3]=f2h(a.w);
  o.s[4]=f2h(b.x); o.s[5]=f2h(b.y); o.s[6]=f2h(b.z); o.s[7]=f2h(b.w);
  ((uint4*)xh)[i8] = o.u;
}

// ---------- kernel 1: WT3[1152][384] = [Wk^T | Wv^T | Wq^T * (log2e/sqrt(H))] fp16 ----------
__global__ __launch_bounds__(256) void k_convert_w(const float* __restrict__ Wq,
                                                   const float* __restrict__ Wk,
                                                   const float* __restrict__ Wv,
                                                   u16* __restrict__ wt3){
  const int idx = blockIdx.x*256 + threadIdx.x;  // 1152*384 exact
  const int n = idx / 384, c = idx % 384;
  const int w = n / 384, h = n % 384;
  const float* W = (w == 0) ? Wk : (w == 1) ? Wv : Wq;
  const float qscale = 1.4426950408889634f * rsqrtf(384.0f);
  const float sc = (w == 2) ? qscale : 1.0f;
  wt3[idx] = f2h(W[c*384 + h] * sc);
}

// ---------- kernel 2: Y[M][1152] = xh[M][384] @ W  (fp16 in, fp32 acc, fp16 out) ----------
__global__ __launch_bounds__(256) void k_gemm(const u16* __restrict__ xh,
                                              const u16* __restrict__ wt3,
                                              u16* __restrict__ y){
  __shared__ u16 As[128*32];
  __shared__ u16 Bs[128*32];
  const int tid = threadIdx.x;
  const int lane = tid & 63, wv = tid >> 6;
  // XCD-bijective swizzle: 9216 = 8 * 1152; co-locate same-m0 blocks on one XCD
  const int wu = (blockIdx.x & 7) * 1152 + (blockIdx.x >> 3);
  const int m0 = (wu / 9) * 128;
  const int n0 = (wu % 9) * 128;
  const int wrow = (wv & 1) * 64, wcol = (wv >> 1) * 64;
  const int q = lane >> 4, c = lane & 15;

  f32x4 acc[4][4];
#pragma unroll
  for (int i = 0; i < 4; ++i)
#pragma unroll
    for (int j = 0; j < 4; ++j) acc[i][j] = (f32x4){0.f,0.f,0.f,0.f};

  const char* xb = (const char*)xh;
  const char* wb = (const char*)wt3;

  for (int ks = 0; ks < 12; ++ks){
    const int k0 = ks * 32;
#pragma unroll
    for (int j = 0; j < 2; ++j){
      const int flat = j*4096 + wv*1024 + lane*16;   // byte offset in 8KB tile
      const int row = flat >> 6, cb = flat & 63;     // 64B per row (32 f16)
      gl_lds16(xb + (size_t)(m0+row)*768 + k0*2 + cb, (char*)As + j*4096 + wv*1024);
      gl_lds16(wb + (size_t)(n0+row)*768 + k0*2 + cb, (char*)Bs + j*4096 + wv*1024);
    }
    __syncthreads();
    f16x8 a[4], b[4];
#pragma unroll
    for (int i = 0; i < 4; ++i)
      a[i] = *(const f16x8*)&As[(wrow + i*16 + c)*32 + q*8];
#pragma unroll
    for (int j = 0; j < 4; ++j)
      b[j] = *(const f16x8*)&Bs[(wcol + j*16 + c)*32 + q*8];
#pragma unroll
    for (int i = 0; i < 4; ++i)
#pragma unroll
      for (int j = 0; j < 4; ++j)
        acc[i][j] = __builtin_amdgcn_mfma_f32_16x16x32_f16(a[i], b[j], acc[i][j], 0, 0, 0);
    __syncthreads();
  }
#pragma unroll
  for (int i = 0; i < 4; ++i)
#pragma unroll
    for (int j = 0; j < 4; ++j)
#pragma unroll
      for (int r = 0; r < 4; ++r){
        const int m = m0 + wrow + i*16 + q*4 + r;    // C/D row = quad*4 + reg
        const int n = n0 + wcol + j*16 + c;          // C/D col = lane&15
        y[(size_t)m*N3 + n] = f2h(acc[i][j][r]);
      }
}

// ---------- kernel 3: vT[b][h][t] = Y[b*T+t][384+h]  (XOR-swizzled LDS transpose) ----------
__global__ __launch_bounds__(256) void k_transpose(const u16* __restrict__ y,
                                                   u16* __restrict__ vT){
  __shared__ u16 s[64*64];
  const int tid = threadIdx.x;
  const int blk = blockIdx.x;
  const int hb = blk % 6, tb = (blk/6) & 3, b = blk / 24;
  const int t0 = tb*64, h0 = hb*64;
#pragma unroll
  for (int it = 0; it < 2; ++it){
    const int flat = it*4096 + tid*16;
    const int tr = flat >> 7;                 // t row (128B per row of 64 h)
    const int he = (flat & 127) >> 1;         // h offset, multiple of 8
    union { uint4 u; u16 v[8]; } d;
    d.u = *(const uint4*)(y + (size_t)(b*Tn + t0 + tr)*N3 + 384 + h0 + he);
    const int hb3 = he >> 3;
#pragma unroll
    for (int e = 0; e < 8; ++e){
      const int h = he + e;
      s[h*64 + (tr & 7) + 8*((tr >> 3) ^ hb3)] = d.v[e];  // swizzled col
    }
  }
  __syncthreads();
#pragma unroll
  for (int it = 0; it < 2; ++it){
    const int flat = it*4096 + tid*16;
    const int hr = flat >> 7;
    const int te = (flat & 127) >> 1;
    const int blkx = (te >> 3) ^ ((hr >> 3) & 7);
    uint4 d = *(const uint4*)&s[hr*64 + blkx*8];
    *(uint4*)(vT + (size_t)b*Hn*Tn + (size_t)(h0+hr)*Tn + t0 + te) = d;
  }
}

// ---------- kernel 4: flash attention, direct-from-L2 K/V fragment reads ----------
// 1 wave = 16 q-rows; block = 4 waves = one 64-row q-tile; grid = 512 batches * 4.
// K/V tiles are L2/LLC-resident (384 KB/batch, 4 blocks of one batch co-XCD via
// swizzle) with only 4-16x reuse -> LDS staging was pure serialization overhead
// (Common-mistake #7). B-fragments are read directly from global (16B/lane,
// 64B-per-row segments); the only LDS left is the wave-private P transpose
// buffer, so the s-tile loop has NO barriers at all: waves run independently
// and the scheduler spreads the 48 QK + 48 PV loads across the MFMAs.
__global__ __launch_bounds__(256, 2) void k_attn(const u16* __restrict__ y,
                                                 const u16* __restrict__ vT,
                                                 float* __restrict__ out){
  __shared__ u16 ps_all[4][16*72];   // per-wave P, padded stride 72
  const int tid = threadIdx.x;
  const int lane = tid & 63, wv = tid >> 6;
  // XCD-bijective swizzle: 2048 = 8 * 256; the 4 q-tile blocks of one batch
  // get consecutive wu -> same XCD -> shared K/V in that XCD's L2.
  const int wu = (blockIdx.x & 7) * 256 + (blockIdx.x >> 3);
  const int b = wu >> 2;
  const int qt = 3 - (wu & 3);       // heavy (4-tile) blocks first per XCD
  const int t0 = qt*64 + wv*16;
  const u16* yb = y  + (size_t)b*Tn*N3;
  const u16* vb = vT + (size_t)b*Hn*Tn;
  u16* ps = ps_all[wv];
  const int q = lane >> 4, c = lane & 15;

  // q A-frags hoisted: loaded once
  f16x8 qf[12];
#pragma unroll
  for (int kk = 0; kk < 12; ++kk)
    qf[kk] = *(const f16x8*)(yb + (size_t)(t0 + c)*N3 + 768 + kk*32 + q*8);

  f32x4 accO[24];
#pragma unroll
  for (int n = 0; n < 24; ++n) accO[n] = (f32x4){0.f,0.f,0.f,0.f};
  float m_i[4] = {-1e30f,-1e30f,-1e30f,-1e30f};
  float l_i[4] = {0.f,0.f,0.f,0.f};

  const int nst = qt + 1;            // uniform across the block's 4 waves
  for (int st = 0; st < nst; ++st){
    const int s0 = st*64;

    // ---- QK^T: 48 MFMAs, b-frags straight from global (K rows, cols 0..383)
    f32x4 accS[4];
#pragma unroll
    for (int j = 0; j < 4; ++j) accS[j] = (f32x4){0.f,0.f,0.f,0.f};
#pragma unroll
    for (int kk = 0; kk < 12; ++kk){
#pragma unroll
      for (int j = 0; j < 4; ++j){
        const f16x8 bf = *(const f16x8*)(yb + (size_t)(s0 + j*16 + c)*N3 + kk*32 + q*8);
        accS[j] = __builtin_amdgcn_mfma_f32_16x16x32_f16(qf[kk], bf, accS[j], 0, 0, 0);
      }
    }

    if (s0 + 63 > t0){               // causal mask (diagonal tiles only)
#pragma unroll
      for (int j = 0; j < 4; ++j){
        const int s = s0 + j*16 + c;
#pragma unroll
        for (int i = 0; i < 4; ++i)
          if (s > t0 + q*4 + i) accS[j][i] = -1e30f;
      }
    }
    float alpha[4];
#pragma unroll
    for (int i = 0; i < 4; ++i){     // online softmax, rows = quad*4+i, 16-lane butterflies
      float mx = fmaxf(fmaxf(accS[0][i], accS[1][i]), fmaxf(accS[2][i], accS[3][i]));
#pragma unroll
      for (int d = 1; d < 16; d <<= 1) mx = fmaxf(mx, __shfl_xor(mx, d, 64));
      const float mnew = fmaxf(m_i[i], mx);
      alpha[i] = exp2f(m_i[i] - mnew);
      m_i[i] = mnew;
      float sum = 0.f;
#pragma unroll
      for (int j = 0; j < 4; ++j){
        const float p = exp2f(accS[j][i] - mnew);   // scores pre-scaled by log2e
        accS[j][i] = p;
        sum += p;
      }
#pragma unroll
      for (int d = 1; d < 16; d <<= 1) sum += __shfl_xor(sum, d, 64);
      l_i[i] = l_i[i]*alpha[i] + sum;
    }
#pragma unroll
    for (int j = 0; j < 4; ++j)      // P: C-layout -> A-layout via wave-private LDS
#pragma unroll
      for (int i = 0; i < 4; ++i)
        ps[(q*4 + i)*72 + j*16 + c] = f2h(accS[j][i]);
#pragma unroll
    for (int n = 0; n < 24; ++n)
#pragma unroll
      for (int i = 0; i < 4; ++i) accO[n][i] *= alpha[i];

    // ---- PV: 48 MFMAs, b-frags straight from global vT (rows h, cols s)
    // ps write->read is same-wave, ordered by lgkmcnt; no barrier needed.
#pragma unroll
    for (int kk = 0; kk < 2; ++kk){
      const f16x8 af = *(const f16x8*)&ps[c*72 + kk*32 + q*8];
#pragma unroll
      for (int n = 0; n < 24; ++n){
        const f16x8 bf = *(const f16x8*)(vb + (size_t)(n*16 + c)*Tn + s0 + kk*32 + q*8);
        accO[n] = __builtin_amdgcn_mfma_f32_16x16x32_f16(af, bf, accO[n], 0, 0, 0);
      }
    }
  }
#pragma unroll
  for (int i = 0; i < 4; ++i){
    const float r = 1.f / l_i[i];
    float* op = out + ((size_t)b*Tn + t0 + q*4 + i)*Hn;
#pragma unroll
    for (int n = 0; n < 24; ++n)
      op[n*16 + c] = accO[n][i] * r;
  }
}

extern "C" void kernel_launch(void* const* d_in, const int* in_sizes, int n_in,
                              void* d_out, int out_size, void* d_ws, size_t ws_size,
                              hipStream_t stream){
  (void)in_sizes; (void)n_in; (void)out_size; (void)ws_size;
  const float* x  = (const float*)d_in[0];
  const float* Wq = (const float*)d_in[1];
  const float* Wk = (const float*)d_in[2];
  const float* Wv = (const float*)d_in[3];
  float* out = (float*)d_out;
  char* ws = (char*)d_ws;

  // ws layout (403,537,920 B total):
  //   [0, 100663296)              xh  (x fp16)  -- dead after k_gemm, reused as vT
  //   [100663296, 402653184)      Y   ([k|v|q] fp16, M x 1152)
  //   [402653184, 403537920)      WT3 fp16
  u16* xh  = (u16*)ws;
  u16* yq  = (u16*)(ws + (size_t)Mn*Cn*2);
  u16* wt3 = (u16*)(ws + (size_t)Mn*Cn*2 + (size_t)Mn*N3*2);
  u16* vT  = xh;

  k_convert_x<<<24576, 256, 0, stream>>>(x, xh);
  k_convert_w<<<1728,  256, 0, stream>>>(Wq, Wk, Wv, wt3);
  k_gemm     <<<9216,  256, 0, stream>>>(xh, wt3, yq);
  k_transpose<<<12288, 256, 0, stream>>>(yq, vT);
  k_attn     <<<2048,  256, 0, stream>>>(yq, vT, out);
}

// Round 2
// 724.041 us; speedup vs baseline: 1.4991x; 1.4991x over previous
//
#include <hip/hip_runtime.h>

#define Bn 512
#define Tn 256
#define Cn 384
#define Hn 384
#define Mn (Bn*Tn)      // 131072 rows
#define N3 1152         // [k|v|q] columns

typedef _Float16 f16x8 __attribute__((ext_vector_type(8)));
typedef float    f32x4 __attribute__((ext_vector_type(4)));
typedef unsigned short u16;
typedef unsigned int   u32;

__device__ inline u16 f2h(float f){
  _Float16 h = (_Float16)f;          // RNE
  return __builtin_bit_cast(u16, h);
}

__device__ inline void gl_lds16(const void* g, void* l){
  __builtin_amdgcn_global_load_lds(
      (const __attribute__((address_space(1))) u32*)g,
      (__attribute__((address_space(3))) u32*)l, 16, 0, 0);
}

// ---------- kernel 0: x fp32 -> fp16 ----------
__global__ __launch_bounds__(256) void k_convert_x(const float* __restrict__ x,
                                                   u16* __restrict__ xh){
  const size_t i8 = (size_t)blockIdx.x*256 + threadIdx.x;  // 8 elems each
  const float4* xp = (const float4*)x;
  float4 a = xp[i8*2], b = xp[i8*2+1];
  union { uint4 u; u16 s[8]; } o;
  o.s[0]=f2h(a.x); o.s[1]=f2h(a.y); o.s[2]=f2h(a.z); o.s[3]=f2h(a.w);
  o.s[4]=f2h(b.x); o.s[5]=f2h(b.y); o.s[6]=f2h(b.z); o.s[7]=f2h(b.w);
  ((uint4*)xh)[i8] = o.u;
}

// ---------- kernel 1: WT3[1152][384] = [Wk^T | Wv^T | Wq^T * (log2e/sqrt(H))] fp16 ----------
__global__ __launch_bounds__(256) void k_convert_w(const float* __restrict__ Wq,
                                                   const float* __restrict__ Wk,
                                                   const float* __restrict__ Wv,
                                                   u16* __restrict__ wt3){
  const int idx = blockIdx.x*256 + threadIdx.x;  // 1152*384 exact
  const int n = idx / 384, c = idx % 384;
  const int w = n / 384, h = n % 384;
  const float* W = (w == 0) ? Wk : (w == 1) ? Wv : Wq;
  const float qscale = 1.4426950408889634f * rsqrtf(384.0f);
  const float sc = (w == 2) ? qscale : 1.0f;
  wt3[idx] = f2h(W[c*384 + h] * sc);
}

// ---------- kernel 2: Y[M][1152] = xh[M][384] @ W  (fp16 in, fp32 acc, fp16 out) ----------
__global__ __launch_bounds__(256) void k_gemm(const u16* __restrict__ xh,
                                              const u16* __restrict__ wt3,
                                              u16* __restrict__ y){
  __shared__ u16 As[128*32];
  __shared__ u16 Bs[128*32];
  const int tid = threadIdx.x;
  const int lane = tid & 63, wv = tid >> 6;
  // XCD-bijective swizzle: 9216 = 8 * 1152; co-locate same-m0 blocks on one XCD
  const int wu = (blockIdx.x & 7) * 1152 + (blockIdx.x >> 3);
  const int m0 = (wu / 9) * 128;
  const int n0 = (wu % 9) * 128;
  const int wrow = (wv & 1) * 64, wcol = (wv >> 1) * 64;
  const int q = lane >> 4, c = lane & 15;

  f32x4 acc[4][4];
#pragma unroll
  for (int i = 0; i < 4; ++i)
#pragma unroll
    for (int j = 0; j < 4; ++j) acc[i][j] = (f32x4){0.f,0.f,0.f,0.f};

  const char* xb = (const char*)xh;
  const char* wb = (const char*)wt3;

  for (int ks = 0; ks < 12; ++ks){
    const int k0 = ks * 32;
#pragma unroll
    for (int j = 0; j < 2; ++j){
      const int flat = j*4096 + wv*1024 + lane*16;   // byte offset in 8KB tile
      const int row = flat >> 6, cb = flat & 63;     // 64B per row (32 f16)
      gl_lds16(xb + (size_t)(m0+row)*768 + k0*2 + cb, (char*)As + j*4096 + wv*1024);
      gl_lds16(wb + (size_t)(n0+row)*768 + k0*2 + cb, (char*)Bs + j*4096 + wv*1024);
    }
    __syncthreads();
    f16x8 a[4], b[4];
#pragma unroll
    for (int i = 0; i < 4; ++i)
      a[i] = *(const f16x8*)&As[(wrow + i*16 + c)*32 + q*8];
#pragma unroll
    for (int j = 0; j < 4; ++j)
      b[j] = *(const f16x8*)&Bs[(wcol + j*16 + c)*32 + q*8];
#pragma unroll
    for (int i = 0; i < 4; ++i)
#pragma unroll
      for (int j = 0; j < 4; ++j)
        acc[i][j] = __builtin_amdgcn_mfma_f32_16x16x32_f16(a[i], b[j], acc[i][j], 0, 0, 0);
    __syncthreads();
  }
#pragma unroll
  for (int i = 0; i < 4; ++i)
#pragma unroll
    for (int j = 0; j < 4; ++j)
#pragma unroll
      for (int r = 0; r < 4; ++r){
        const int m = m0 + wrow + i*16 + q*4 + r;    // C/D row = quad*4 + reg
        const int n = n0 + wcol + j*16 + c;          // C/D col = lane&15
        y[(size_t)m*N3 + n] = f2h(acc[i][j][r]);
      }
}

// ---------- kernel 3: vT[b][h][t] = Y[b*T+t][384+h]  (XOR-swizzled LDS transpose) ----------
__global__ __launch_bounds__(256) void k_transpose(const u16* __restrict__ y,
                                                   u16* __restrict__ vT){
  __shared__ u16 s[64*64];
  const int tid = threadIdx.x;
  const int blk = blockIdx.x;
  const int hb = blk % 6, tb = (blk/6) & 3, b = blk / 24;
  const int t0 = tb*64, h0 = hb*64;
#pragma unroll
  for (int it = 0; it < 2; ++it){
    const int flat = it*4096 + tid*16;
    const int tr = flat >> 7;                 // t row (128B per row of 64 h)
    const int he = (flat & 127) >> 1;         // h offset, multiple of 8
    union { uint4 u; u16 v[8]; } d;
    d.u = *(const uint4*)(y + (size_t)(b*Tn + t0 + tr)*N3 + 384 + h0 + he);
    const int hb3 = he >> 3;
#pragma unroll
    for (int e = 0; e < 8; ++e){
      const int h = he + e;
      s[h*64 + (tr & 7) + 8*((tr >> 3) ^ hb3)] = d.v[e];  // swizzled col
    }
  }
  __syncthreads();
#pragma unroll
  for (int it = 0; it < 2; ++it){
    const int flat = it*4096 + tid*16;
    const int hr = flat >> 7;
    const int te = (flat & 127) >> 1;
    const int blkx = (te >> 3) ^ ((hr >> 3) & 7);
    uint4 d = *(const uint4*)&s[hr*64 + blkx*8];
    *(uint4*)(vT + (size_t)b*Hn*Tn + (size_t)(h0+hr)*Tn + t0 + te) = d;
  }
}

// ---------- kernel 4: flash attention, ping-pong LDS staging, counted vmcnt ----------
// 128 q-rows per block (8 waves x 16 rows), KVBLK=64; grid = 512 batches * 2.
// Separate K (48KB) and V (48KB) LDS buffers. Per s-tile the schedule is
//   QK -> bar -> issue K[st+1] -> vmcnt(6) [V[st] done] -> bar -> PV
//      -> bar -> issue V[st+1] -> vmcnt(6) [K[st+1] done] -> bar
// so steady-state never drains vmcnt to 0 (T3/T4): each stage's HBM/L2 latency
// is covered by a full compute phase. Raw s_barrier + inline-asm counted waits
// (the verified 8-phase pattern). The ONLY vmem ops in the loop are our 6+6
// gl_lds per wave, so the vmcnt arithmetic is exact. ps is wave-private
// (same-wave ds ordering, verified round 1). Waves fully above an s-tile skip
// compute but still stage + hit barriers.
__global__ __launch_bounds__(512, 2) void k_attn(const u16* __restrict__ y,
                                                 const u16* __restrict__ vT,
                                                 float* __restrict__ out){
  __shared__ u16 Ks[64*384];         // 48 KB K-tile (s rows, 384 h-cols)
  __shared__ u16 Vs[384*64];         // 48 KB vT-tile (h rows, 64 s-cols)
  __shared__ u16 ps_all[8][16*72];   // per-wave P, padded stride 72 (18 KB)
  const int tid = threadIdx.x;
  const int lane = tid & 63, wv = tid >> 6;
  // XCD swizzle: 1024 = 8 * 128; both blocks of one batch on one XCD (L2 K/V
  // sharing); heavy (qt=1, 4-tile) blocks dispatched first.
  const int xcd = blockIdx.x & 7, lix = blockIdx.x >> 3;
  const int qt = (lix < 64) ? 1 : 0;
  const int b = xcd*64 + (lix & 63);
  const int t0 = qt*128 + wv*16;
  const u16* yb = y  + (size_t)b*Tn*N3;
  const u16* vb = vT + (size_t)b*Hn*Tn;
  u16* ps = ps_all[wv];
  const int q = lane >> 4, c = lane & 15;

  // q A-frags hoisted: loaded once
  f16x8 qf[12];
#pragma unroll
  for (int kk = 0; kk < 12; ++kk)
    qf[kk] = *(const f16x8*)(yb + (size_t)(t0 + c)*N3 + 768 + kk*32 + q*8);

  f32x4 accO[24];
#pragma unroll
  for (int n = 0; n < 24; ++n) accO[n] = (f32x4){0.f,0.f,0.f,0.f};
  float m_i[4] = {-1e30f,-1e30f,-1e30f,-1e30f};
  float l_i[4] = {0.f,0.f,0.f,0.f};

  const int nst = qt*2 + 2;          // 2 or 4 s-tiles, uniform per block

  // stage K-tile: rows s0..s0+63, cols 0..383; 3072 16B-slots, 6 per thread.
  // 16B-group XOR swizzle applied to the global source (gl_lds dest is linear).
  auto stageK = [&](int s0){
#pragma unroll
    for (int it = 0; it < 6; ++it){
      const int slot = it*512 + tid;          // LDS 16B-slot = r*48 + gs
      const int r = slot / 48, gs = slot % 48;
      const int g = (gs & ~7) | ((gs & 7) ^ (r & 7));
      gl_lds16(yb + (size_t)(s0 + r)*N3 + g*8, (char*)Ks + (it*8 + wv)*1024);
    }
  };
  // stage vT-tile: rows h=0..383, cols s0..s0+63 (8 16B-groups per row)
  auto stageV = [&](int s0){
#pragma unroll
    for (int it = 0; it < 6; ++it){
      const int slot = it*512 + tid;          // LDS 16B-slot = h*8 + gsv
      const int h = slot >> 3, gsv = slot & 7;
      const int g = gsv ^ (h & 7);
      gl_lds16(vb + (size_t)h*Tn + s0 + g*8, (char*)Vs + (it*8 + wv)*1024);
    }
  };

  // prologue: queue [K0(6), V0(6)] -> wait K0 -> everyone K0 done
  stageK(0);
  stageV(0);
  asm volatile("s_waitcnt vmcnt(6)" ::: "memory");
  __builtin_amdgcn_s_barrier();
  asm volatile("" ::: "memory");

  for (int st = 0; st < nst; ++st){
    const int s0 = st*64;
    const bool active = (s0 <= t0 + 15);      // tile intersects causal region

    if (active){
      // ---- QK^T: 48 MFMAs, b-frags from Ks, a-frags from registers
      f32x4 accS[4];
#pragma unroll
      for (int j = 0; j < 4; ++j) accS[j] = (f32x4){0.f,0.f,0.f,0.f};
#pragma unroll
      for (int kk = 0; kk < 12; ++kk){
#pragma unroll
        for (int j = 0; j < 4; ++j){
          const int s = j*16 + c;
          const int g = kk*4 + q;
          const int gs = (g & ~7) | ((g & 7) ^ (c & 7));  // s&7 == c&7
          const f16x8 bf = *(const f16x8*)&Ks[(s*48 + gs)*8];
          accS[j] = __builtin_amdgcn_mfma_f32_16x16x32_f16(qf[kk], bf, accS[j], 0, 0, 0);
        }
      }

      if (s0 + 63 > t0){             // causal mask (diagonal tiles only)
#pragma unroll
        for (int j = 0; j < 4; ++j){
          const int s = s0 + j*16 + c;
#pragma unroll
          for (int i = 0; i < 4; ++i)
            if (s > t0 + q*4 + i) accS[j][i] = -1e30f;
        }
      }
      float alpha[4];
#pragma unroll
      for (int i = 0; i < 4; ++i){   // online softmax, rows = quad*4+i
        float mx = fmaxf(fmaxf(accS[0][i], accS[1][i]), fmaxf(accS[2][i], accS[3][i]));
#pragma unroll
        for (int d = 1; d < 16; d <<= 1) mx = fmaxf(mx, __shfl_xor(mx, d, 64));
        const float mnew = fmaxf(m_i[i], mx);
        alpha[i] = exp2f(m_i[i] - mnew);
        m_i[i] = mnew;
        float sum = 0.f;
#pragma unroll
        for (int j = 0; j < 4; ++j){
          const float p = exp2f(accS[j][i] - mnew);   // scores pre-scaled by log2e
          accS[j][i] = p;
          sum += p;
        }
#pragma unroll
        for (int d = 1; d < 16; d <<= 1) sum += __shfl_xor(sum, d, 64);
        l_i[i] = l_i[i]*alpha[i] + sum;
      }
#pragma unroll
      for (int j = 0; j < 4; ++j)    // P: C-layout -> A-layout via wave-private LDS
#pragma unroll
        for (int i = 0; i < 4; ++i)
          ps[(q*4 + i)*72 + j*16 + c] = f2h(accS[j][i]);
#pragma unroll
      for (int n = 0; n < 24; ++n)
#pragma unroll
        for (int i = 0; i < 4; ++i) accO[n][i] *= alpha[i];
    }

    __builtin_amdgcn_s_barrier();    // B1: all QK reads of Ks consumed
    asm volatile("" ::: "memory");
    if (st + 1 < nst){
      stageK(s0 + 64);               // queue [V_st(6), K_next(6)]
      asm volatile("s_waitcnt vmcnt(6)" ::: "memory");  // V[st] done
    } else {
      asm volatile("s_waitcnt vmcnt(0)" ::: "memory");  // V[st] done (tail)
    }
    __builtin_amdgcn_s_barrier();    // B2: everyone's V[st] resident
    asm volatile("" ::: "memory");

    if (active){
      // ---- PV: 48 MFMAs, b-frags from Vs, a-frags (P) from wave-private LDS
#pragma unroll
      for (int kk = 0; kk < 2; ++kk){
        const f16x8 af = *(const f16x8*)&ps[c*72 + kk*32 + q*8];
#pragma unroll
        for (int n = 0; n < 24; ++n){
          const int h = n*16 + c;
          const int gs = (kk*4 + q) ^ (c & 7);          // h&7 == c&7
          const f16x8 bf = *(const f16x8*)&Vs[(h*8 + gs)*8];
          accO[n] = __builtin_amdgcn_mfma_f32_16x16x32_f16(af, bf, accO[n], 0, 0, 0);
        }
      }
    }

    __builtin_amdgcn_s_barrier();    // B3: all PV reads of Vs consumed
    asm volatile("" ::: "memory");
    if (st + 1 < nst){
      stageV(s0 + 64);               // queue [K_next(6), V_next(6)]
      asm volatile("s_waitcnt vmcnt(6)" ::: "memory");  // K[st+1] done
      __builtin_amdgcn_s_barrier();  // B4: everyone's K[st+1] resident
      asm volatile("" ::: "memory");
    }
  }

#pragma unroll
  for (int i = 0; i < 4; ++i){
    const float r = 1.f / l_i[i];
    float* op = out + ((size_t)b*Tn + t0 + q*4 + i)*Hn;
#pragma unroll
    for (int n = 0; n < 24; ++n)
      op[n*16 + c] = accO[n][i] * r;
  }
}

extern "C" void kernel_launch(void* const* d_in, const int* in_sizes, int n_in,
                              void* d_out, int out_size, void* d_ws, size_t ws_size,
                              hipStream_t stream){
  (void)in_sizes; (void)n_in; (void)out_size; (void)ws_size;
  const float* x  = (const float*)d_in[0];
  const float* Wq = (const float*)d_in[1];
  const float* Wk = (const float*)d_in[2];
  const float* Wv = (const float*)d_in[3];
  float* out = (float*)d_out;
  char* ws = (char*)d_ws;

  // ws layout (403,537,920 B total):
  //   [0, 100663296)              xh  (x fp16)  -- dead after k_gemm, reused as vT
  //   [100663296, 402653184)      Y   ([k|v|q] fp16, M x 1152)
  //   [402653184, 403537920)      WT3 fp16
  u16* xh  = (u16*)ws;
  u16* yq  = (u16*)(ws + (size_t)Mn*Cn*2);
  u16* wt3 = (u16*)(ws + (size_t)Mn*Cn*2 + (size_t)Mn*N3*2);
  u16* vT  = xh;

  k_convert_x<<<24576, 256, 0, stream>>>(x, xh);
  k_convert_w<<<1728,  256, 0, stream>>>(Wq, Wk, Wv, wt3);
  k_gemm     <<<9216,  256, 0, stream>>>(xh, wt3, yq);
  k_transpose<<<12288, 256, 0, stream>>>(yq, vT);
  k_attn     <<<1024,  512, 0, stream>>>(yq, vT, out);
}

// Round 3
// 718.866 us; speedup vs baseline: 1.5099x; 1.0072x over previous
//
#include <hip/hip_runtime.h>

#define Bn 512
#define Tn 256
#define Cn 384
#define Hn 384
#define Mn (Bn*Tn)      // 131072 rows
#define N3 1152         // [k|v|q] columns

typedef _Float16 f16x8 __attribute__((ext_vector_type(8)));
typedef float    f32x4 __attribute__((ext_vector_type(4)));
typedef unsigned short u16;
typedef unsigned int   u32;

__device__ inline u16 f2h(float f){
  _Float16 h = (_Float16)f;          // RNE
  return __builtin_bit_cast(u16, h);
}

__device__ inline void gl_lds16(const void* g, void* l){
  __builtin_amdgcn_global_load_lds(
      (const __attribute__((address_space(1))) u32*)g,
      (__attribute__((address_space(3))) u32*)l, 16, 0, 0);
}

// ---------- kernel 0: x fp32 -> fp16 ----------
__global__ __launch_bounds__(256) void k_convert_x(const float* __restrict__ x,
                                                   u16* __restrict__ xh){
  const size_t i8 = (size_t)blockIdx.x*256 + threadIdx.x;  // 8 elems each
  const float4* xp = (const float4*)x;
  float4 a = xp[i8*2], b = xp[i8*2+1];
  union { uint4 u; u16 s[8]; } o;
  o.s[0]=f2h(a.x); o.s[1]=f2h(a.y); o.s[2]=f2h(a.z); o.s[3]=f2h(a.w);
  o.s[4]=f2h(b.x); o.s[5]=f2h(b.y); o.s[6]=f2h(b.z); o.s[7]=f2h(b.w);
  ((uint4*)xh)[i8] = o.u;
}

// ---------- kernel 1: WT3[1152][384] = [Wk^T | Wv^T | Wq^T * (log2e/sqrt(H))] fp16 ----------
__global__ __launch_bounds__(256) void k_convert_w(const float* __restrict__ Wq,
                                                   const float* __restrict__ Wk,
                                                   const float* __restrict__ Wv,
                                                   u16* __restrict__ wt3){
  const int idx = blockIdx.x*256 + threadIdx.x;  // 1152*384 exact
  const int n = idx / 384, c = idx % 384;
  const int w = n / 384, h = n % 384;
  const float* W = (w == 0) ? Wk : (w == 1) ? Wv : Wq;
  const float qscale = 1.4426950408889634f * rsqrtf(384.0f);
  const float sc = (w == 2) ? qscale : 1.0f;
  wt3[idx] = f2h(W[c*384 + h] * sc);
}

// ---------- kernel 2: Y[M][1152] = xh[M][384] @ W  (fp16 in, fp32 acc, fp16 out) ----------
// Triple-buffered staging with counted vmcnt (never a cold drain in steady state):
//   prologue: stage t=0,1,2 (12 loads) ; vmcnt(8) ; bar
//   iter t  : compute buf[t%3] ; bar ; stage t+3 into buf[t%3] ; vmcnt(8|4|0) ; bar
// LDS fragment reads XOR-swizzled (16B-group g ^= (row&3)^((row>>2)&3), applied to
// the *global source* since gl_lds writes linearly) -> 2 lanes/bank-group (free).
__global__ __launch_bounds__(256, 3) void k_gemm(const u16* __restrict__ xh,
                                                 const u16* __restrict__ wt3,
                                                 u16* __restrict__ y){
  __shared__ u16 As[3][128*32];      // 3 x 8 KB
  __shared__ u16 Bs[3][128*32];      // 3 x 8 KB  (48 KB total)
  const int tid = threadIdx.x;
  const int lane = tid & 63, wv = tid >> 6;
  // XCD-bijective swizzle: 9216 = 8 * 1152; co-locate same-m0 blocks on one XCD
  const int wu = (blockIdx.x & 7) * 1152 + (blockIdx.x >> 3);
  const int m0 = (wu / 9) * 128;
  const int n0 = (wu % 9) * 128;
  const int wrow = (wv & 1) * 64, wcol = (wv >> 1) * 64;
  const int q = lane >> 4, c = lane & 15;

  f32x4 acc[4][4];
#pragma unroll
  for (int i = 0; i < 4; ++i)
#pragma unroll
    for (int j = 0; j < 4; ++j) acc[i][j] = (f32x4){0.f,0.f,0.f,0.f};

  const char* xb = (const char*)xh;
  const char* wb = (const char*)wt3;

  // stage one 128x32-half k-tile of A and B into buffer `buf` (4 gl_lds/thread)
  auto stage = [&](int buf, int ks){
#pragma unroll
    for (int j = 0; j < 2; ++j){
      const int flat = j*4096 + wv*1024 + lane*16;   // byte offset in 8KB tile
      const int row = flat >> 6;                     // 64B per row (32 f16)
      const int gb = (flat >> 4) & 3;                // 16B group within row
      const int g = gb ^ ((row & 3) ^ ((row >> 2) & 3));  // src group (swizzle)
      gl_lds16(xb + (size_t)(m0+row)*768 + ks*64 + g*16, (char*)As[buf] + flat);
      gl_lds16(wb + (size_t)(n0+row)*768 + ks*64 + g*16, (char*)Bs[buf] + flat);
    }
  };

  stage(0, 0);
  stage(1, 1);
  stage(2, 2);                       // 12 outstanding
  asm volatile("s_waitcnt vmcnt(8)" ::: "memory");   // tile 0 resident (this wave)
  __builtin_amdgcn_s_barrier();      // ... for all waves
  asm volatile("" ::: "memory");

  const int vsw = (c & 3) ^ ((c >> 2) & 3);          // read-side swizzle (row bits = c bits)
#pragma unroll
  for (int t = 0; t < 12; ++t){
    const int cur = t % 3;
    f16x8 a[4], b[4];
#pragma unroll
    for (int i = 0; i < 4; ++i)
      a[i] = *(const f16x8*)&As[cur][(wrow + i*16 + c)*32 + ((q ^ vsw)*8)];
#pragma unroll
    for (int j = 0; j < 4; ++j)
      b[j] = *(const f16x8*)&Bs[cur][(wcol + j*16 + c)*32 + ((q ^ vsw)*8)];
    __builtin_amdgcn_s_setprio(1);
#pragma unroll
    for (int i = 0; i < 4; ++i)
#pragma unroll
      for (int j = 0; j < 4; ++j)
        acc[i][j] = __builtin_amdgcn_mfma_f32_16x16x32_f16(a[i], b[j], acc[i][j], 0, 0, 0);
    __builtin_amdgcn_s_setprio(0);
    if (t == 11) break;              // last tile: straight to epilogue
    __builtin_amdgcn_s_barrier();    // all waves done reading buf[cur]
    asm volatile("" ::: "memory");
    if (t + 3 < 12) stage(cur, t + 3);               // refill consumed buffer
    if (t < 9)       asm volatile("s_waitcnt vmcnt(8)" ::: "memory");  // stage(t+1) done
    else if (t == 9) asm volatile("s_waitcnt vmcnt(4)" ::: "memory");
    else             asm volatile("s_waitcnt vmcnt(0)" ::: "memory");
    __builtin_amdgcn_s_barrier();    // stage(t+1) resident for all waves
    asm volatile("" ::: "memory");
  }
#pragma unroll
  for (int i = 0; i < 4; ++i)
#pragma unroll
    for (int j = 0; j < 4; ++j)
#pragma unroll
      for (int r = 0; r < 4; ++r){
        const int m = m0 + wrow + i*16 + q*4 + r;    // C/D row = quad*4 + reg
        const int n = n0 + wcol + j*16 + c;          // C/D col = lane&15
        y[(size_t)m*N3 + n] = f2h(acc[i][j][r]);
      }
}

// ---------- kernel 3: vT[b][h][t] = Y[b*T+t][384+h]  (XOR-swizzled LDS transpose) ----------
__global__ __launch_bounds__(256) void k_transpose(const u16* __restrict__ y,
                                                   u16* __restrict__ vT){
  __shared__ u16 s[64*64];
  const int tid = threadIdx.x;
  const int blk = blockIdx.x;
  const int hb = blk % 6, tb = (blk/6) & 3, b = blk / 24;
  const int t0 = tb*64, h0 = hb*64;
#pragma unroll
  for (int it = 0; it < 2; ++it){
    const int flat = it*4096 + tid*16;
    const int tr = flat >> 7;                 // t row (128B per row of 64 h)
    const int he = (flat & 127) >> 1;         // h offset, multiple of 8
    union { uint4 u; u16 v[8]; } d;
    d.u = *(const uint4*)(y + (size_t)(b*Tn + t0 + tr)*N3 + 384 + h0 + he);
    const int hb3 = he >> 3;
#pragma unroll
    for (int e = 0; e < 8; ++e){
      const int h = he + e;
      s[h*64 + (tr & 7) + 8*((tr >> 3) ^ hb3)] = d.v[e];  // swizzled col
    }
  }
  __syncthreads();
#pragma unroll
  for (int it = 0; it < 2; ++it){
    const int flat = it*4096 + tid*16;
    const int hr = flat >> 7;
    const int te = (flat & 127) >> 1;
    const int blkx = (te >> 3) ^ ((hr >> 3) & 7);
    uint4 d = *(const uint4*)&s[hr*64 + blkx*8];
    *(uint4*)(vT + (size_t)b*Hn*Tn + (size_t)(h0+hr)*Tn + t0 + te) = d;
  }
}

// ---------- kernel 4: flash attention, ping-pong LDS staging, counted vmcnt ----------
// (structure verified round 2: 724us total, attn out of top-5; this round only
//  adds s_setprio(1) around the MFMA clusters -- T5, now that the schedule is
//  phase-split.)
__global__ __launch_bounds__(512, 2) void k_attn(const u16* __restrict__ y,
                                                 const u16* __restrict__ vT,
                                                 float* __restrict__ out){
  __shared__ u16 Ks[64*384];         // 48 KB K-tile (s rows, 384 h-cols)
  __shared__ u16 Vs[384*64];         // 48 KB vT-tile (h rows, 64 s-cols)
  __shared__ u16 ps_all[8][16*72];   // per-wave P, padded stride 72 (18 KB)
  const int tid = threadIdx.x;
  const int lane = tid & 63, wv = tid >> 6;
  const int xcd = blockIdx.x & 7, lix = blockIdx.x >> 3;
  const int qt = (lix < 64) ? 1 : 0;
  const int b = xcd*64 + (lix & 63);
  const int t0 = qt*128 + wv*16;
  const u16* yb = y  + (size_t)b*Tn*N3;
  const u16* vb = vT + (size_t)b*Hn*Tn;
  u16* ps = ps_all[wv];
  const int q = lane >> 4, c = lane & 15;

  f16x8 qf[12];
#pragma unroll
  for (int kk = 0; kk < 12; ++kk)
    qf[kk] = *(const f16x8*)(yb + (size_t)(t0 + c)*N3 + 768 + kk*32 + q*8);

  f32x4 accO[24];
#pragma unroll
  for (int n = 0; n < 24; ++n) accO[n] = (f32x4){0.f,0.f,0.f,0.f};
  float m_i[4] = {-1e30f,-1e30f,-1e30f,-1e30f};
  float l_i[4] = {0.f,0.f,0.f,0.f};

  const int nst = qt*2 + 2;          // 2 or 4 s-tiles, uniform per block

  auto stageK = [&](int s0){
#pragma unroll
    for (int it = 0; it < 6; ++it){
      const int slot = it*512 + tid;          // LDS 16B-slot = r*48 + gs
      const int r = slot / 48, gs = slot % 48;
      const int g = (gs & ~7) | ((gs & 7) ^ (r & 7));
      gl_lds16(yb + (size_t)(s0 + r)*N3 + g*8, (char*)Ks + (it*8 + wv)*1024);
    }
  };
  auto stageV = [&](int s0){
#pragma unroll
    for (int it = 0; it < 6; ++it){
      const int slot = it*512 + tid;          // LDS 16B-slot = h*8 + gsv
      const int h = slot >> 3, gsv = slot & 7;
      const int g = gsv ^ (h & 7);
      gl_lds16(vb + (size_t)h*Tn + s0 + g*8, (char*)Vs + (it*8 + wv)*1024);
    }
  };

  stageK(0);
  stageV(0);
  asm volatile("s_waitcnt vmcnt(6)" ::: "memory");
  __builtin_amdgcn_s_barrier();
  asm volatile("" ::: "memory");

  for (int st = 0; st < nst; ++st){
    const int s0 = st*64;
    const bool active = (s0 <= t0 + 15);      // tile intersects causal region

    if (active){
      f32x4 accS[4];
#pragma unroll
      for (int j = 0; j < 4; ++j) accS[j] = (f32x4){0.f,0.f,0.f,0.f};
      __builtin_amdgcn_s_setprio(1);
#pragma unroll
      for (int kk = 0; kk < 12; ++kk){
#pragma unroll
        for (int j = 0; j < 4; ++j){
          const int s = j*16 + c;
          const int g = kk*4 + q;
          const int gs = (g & ~7) | ((g & 7) ^ (c & 7));  // s&7 == c&7
          const f16x8 bf = *(const f16x8*)&Ks[(s*48 + gs)*8];
          accS[j] = __builtin_amdgcn_mfma_f32_16x16x32_f16(qf[kk], bf, accS[j], 0, 0, 0);
        }
      }
      __builtin_amdgcn_s_setprio(0);

      if (s0 + 63 > t0){             // causal mask (diagonal tiles only)
#pragma unroll
        for (int j = 0; j < 4; ++j){
          const int s = s0 + j*16 + c;
#pragma unroll
          for (int i = 0; i < 4; ++i)
            if (s > t0 + q*4 + i) accS[j][i] = -1e30f;
        }
      }
      float alpha[4];
#pragma unroll
      for (int i = 0; i < 4; ++i){   // online softmax, rows = quad*4+i
        float mx = fmaxf(fmaxf(accS[0][i], accS[1][i]), fmaxf(accS[2][i], accS[3][i]));
#pragma unroll
        for (int d = 1; d < 16; d <<= 1) mx = fmaxf(mx, __shfl_xor(mx, d, 64));
        const float mnew = fmaxf(m_i[i], mx);
        alpha[i] = exp2f(m_i[i] - mnew);
        m_i[i] = mnew;
        float sum = 0.f;
#pragma unroll
        for (int j = 0; j < 4; ++j){
          const float p = exp2f(accS[j][i] - mnew);   // scores pre-scaled by log2e
          accS[j][i] = p;
          sum += p;
        }
#pragma unroll
        for (int d = 1; d < 16; d <<= 1) sum += __shfl_xor(sum, d, 64);
        l_i[i] = l_i[i]*alpha[i] + sum;
      }
#pragma unroll
      for (int j = 0; j < 4; ++j)    // P: C-layout -> A-layout via wave-private LDS
#pragma unroll
        for (int i = 0; i < 4; ++i)
          ps[(q*4 + i)*72 + j*16 + c] = f2h(accS[j][i]);
#pragma unroll
      for (int n = 0; n < 24; ++n)
#pragma unroll
        for (int i = 0; i < 4; ++i) accO[n][i] *= alpha[i];
    }

    __builtin_amdgcn_s_barrier();    // B1: all QK reads of Ks consumed
    asm volatile("" ::: "memory");
    if (st + 1 < nst){
      stageK(s0 + 64);               // queue [V_st(6), K_next(6)]
      asm volatile("s_waitcnt vmcnt(6)" ::: "memory");  // V[st] done
    } else {
      asm volatile("s_waitcnt vmcnt(0)" ::: "memory");  // V[st] done (tail)
    }
    __builtin_amdgcn_s_barrier();    // B2: everyone's V[st] resident
    asm volatile("" ::: "memory");

    if (active){
      __builtin_amdgcn_s_setprio(1);
#pragma unroll
      for (int kk = 0; kk < 2; ++kk){
        const f16x8 af = *(const f16x8*)&ps[c*72 + kk*32 + q*8];
#pragma unroll
        for (int n = 0; n < 24; ++n){
          const int h = n*16 + c;
          const int gs = (kk*4 + q) ^ (c & 7);          // h&7 == c&7
          const f16x8 bf = *(const f16x8*)&Vs[(h*8 + gs)*8];
          accO[n] = __builtin_amdgcn_mfma_f32_16x16x32_f16(af, bf, accO[n], 0, 0, 0);
        }
      }
      __builtin_amdgcn_s_setprio(0);
    }

    __builtin_amdgcn_s_barrier();    // B3: all PV reads of Vs consumed
    asm volatile("" ::: "memory");
    if (st + 1 < nst){
      stageV(s0 + 64);               // queue [K_next(6), V_next(6)]
      asm volatile("s_waitcnt vmcnt(6)" ::: "memory");  // K[st+1] done
      __builtin_amdgcn_s_barrier();  // B4: everyone's K[st+1] resident
      asm volatile("" ::: "memory");
    }
  }

#pragma unroll
  for (int i = 0; i < 4; ++i){
    const float r = 1.f / l_i[i];
    float* op = out + ((size_t)b*Tn + t0 + q*4 + i)*Hn;
#pragma unroll
    for (int n = 0; n < 24; ++n)
      op[n*16 + c] = accO[n][i] * r;
  }
}

extern "C" void kernel_launch(void* const* d_in, const int* in_sizes, int n_in,
                              void* d_out, int out_size, void* d_ws, size_t ws_size,
                              hipStream_t stream){
  (void)in_sizes; (void)n_in; (void)out_size; (void)ws_size;
  const float* x  = (const float*)d_in[0];
  const float* Wq = (const float*)d_in[1];
  const float* Wk = (const float*)d_in[2];
  const float* Wv = (const float*)d_in[3];
  float* out = (float*)d_out;
  char* ws = (char*)d_ws;

  // ws layout (403,537,920 B total):
  //   [0, 100663296)              xh  (x fp16)  -- dead after k_gemm, reused as vT
  //   [100663296, 402653184)      Y   ([k|v|q] fp16, M x 1152)
  //   [402653184, 403537920)      WT3 fp16
  u16* xh  = (u16*)ws;
  u16* yq  = (u16*)(ws + (size_t)Mn*Cn*2);
  u16* wt3 = (u16*)(ws + (size_t)Mn*Cn*2 + (size_t)Mn*N3*2);
  u16* vT  = xh;

  k_convert_x<<<24576, 256, 0, stream>>>(x, xh);
  k_convert_w<<<1728,  256, 0, stream>>>(Wq, Wk, Wv, wt3);
  k_gemm     <<<9216,  256, 0, stream>>>(xh, wt3, yq);
  k_transpose<<<12288, 256, 0, stream>>>(yq, vT);
  k_attn     <<<1024,  512, 0, stream>>>(yq, vT, out);
}